// Round 8
// baseline (945.649 us; speedup 1.0000x reference)
//
#include <hip/hip_runtime.h>
#include <math.h>

#define LN    524288        // signal length, 2^19
#define N1    512           // first-FFT length (column FFT)
#define N2    1024          // second-FFT length (row FFT)
#define NCH   129
#define DSR   80            // downsample rate
#define NOUT  6553          // output frames per channel
#define OB2   64            // outputs per IIR block
#define NBLK  103           // ceil(NOUT/OB2)
#define SPB   (OB2*DSR)     // 5120 samples per IIR block
#define TPW   20            // samples per thread in IIR
#define NPAIR 65            // ceil(129/2) channel pairs
#define KTAIL 48            // LN - NOUT*DSR

__device__ __forceinline__ float2 cmulf(float2 a, float2 b) {
    return make_float2(a.x*b.x - a.y*b.y, a.x*b.y + a.y*b.x);
}

// fast |x|^a * sign(x): hardware log2/exp2 (x=0 -> -inf -> 0, correct)
__device__ __forceinline__ float powsign(float x, float a) {
    float m = __builtin_amdgcn_exp2f(a * __builtin_amdgcn_logf(fabsf(x)));
    return copysignf(m, x);
}

// ---------------- pack real x into complex buffer ----------------
__global__ void pack_x(const float* __restrict__ x, float2* __restrict__ dst) {
    int i = blockIdx.x * 256 + threadIdx.x;
    dst[i] = make_float2(x[i], 0.f);
}

// ---------------- tiled complex transpose (forward path only) ----------------
__global__ void transpose_c(const float2* __restrict__ src, float2* __restrict__ dst,
                            int R, int Cc) {
    __shared__ float2 tile[32][33];
    size_t boff = (size_t)blockIdx.z * LN;
    src += boff; dst += boff;
    int x  = blockIdx.x * 32 + threadIdx.x;
    int y0 = blockIdx.y * 32 + threadIdx.y;
#pragma unroll
    for (int i = 0; i < 32; i += 8)
        tile[threadIdx.y + i][threadIdx.x] = src[(size_t)(y0 + i) * Cc + x];
    __syncthreads();
    int xo  = blockIdx.y * 32 + threadIdx.x;
    int yo0 = blockIdx.x * 32 + threadIdx.y;
#pragma unroll
    for (int i = 0; i < 32; i += 8)
        dst[(size_t)(yo0 + i) * R + xo] = tile[threadIdx.x][threadIdx.y + i];
}

// ---------------- LDS Stockham radix-2 row FFT, natural in/out, LDS twiddle table -----
template<int M, int SIGN, int TW>
__global__ __launch_bounds__(256) void fft_rows(const float2* __restrict__ src,
                                                float2* __restrict__ dst,
                                                int rows_per_batch) {
    __shared__ float2 ping[M];
    __shared__ float2 pong[M];
    __shared__ float2 twid[M];       // twid[Ns+jm] = e^{SIGN*i*pi*jm/Ns}
    size_t rowg = blockIdx.x;
    const float2* srow = src + rowg * M;
    float2* drow = dst + rowg * M;
    int row = (int)(rowg % (size_t)rows_per_batch);
    int t = threadIdx.x;
    for (int i = t; i < M; i += 256) {
        ping[i] = srow[i];
        if (i >= 1) {
            int h = 1 << (31 - __clz((unsigned)i));
            float ang = (float)SIGN * 3.14159265358979323846f * (float)(i - h) / (float)h;
            float s, c; __sincosf(ang, &s, &c);
            twid[i] = make_float2(c, s);
        }
    }
    __syncthreads();
    float2* a = ping;
    float2* b = pong;
    for (int Ns = 1; Ns < M; Ns <<= 1) {
        for (int j = t; j < M/2; j += 256) {
            int jm = j & (Ns - 1);
            float2 v0 = a[j];
            float2 v1 = a[j + M/2];
            float2 tw = twid[Ns + jm];
            float2 w = make_float2(v1.x*tw.x - v1.y*tw.y, v1.x*tw.y + v1.y*tw.x);
            int d0 = ((j & ~(Ns - 1)) << 1) | jm;
            b[d0]      = make_float2(v0.x + w.x, v0.y + w.y);
            b[d0 + Ns] = make_float2(v0.x - w.x, v0.y - w.y);
        }
        __syncthreads();
        float2* tmp = a; a = b; b = tmp;
    }
    if (TW) {
        const float c2pi = 6.28318530717958647692f / (float)LN;
        for (int i = t; i < M; i += 256) {
            float2 v = a[i];
            unsigned prod = ((unsigned)row * (unsigned)i) & (unsigned)(LN - 1);
            float ang = (float)SIGN * c2pi * (float)prod;
            float s, c;
            __sincosf(ang, &s, &c);
            drow[i] = make_float2(v.x*c - v.y*s, v.x*s + v.y*c);
        }
    } else {
        for (int i = t; i < M; i += 256) drow[i] = a[i];
    }
}

// ---------------- Hermitian-combine W[k],W[L-k] from H,X (X real => X[L-k]=conj X[k]) ----
__device__ __forceinline__ void herm2(float2 X1,
                                      float har,  float hai,  float hbr,  float hbi,
                                      float har2, float hai2, float hbr2, float hbi2,
                                      bool hasB, float2& Wk, float2& WkL) {
    float2 a1 = make_float2(har*X1.x - hai*X1.y, har*X1.y + hai*X1.x);
    float2 a2 = make_float2(har2*X1.x + hai2*X1.y, hai2*X1.x - har2*X1.y);
    float yar = 0.5f*(a1.x + a2.x), yai = 0.5f*(a1.y - a2.y);
    float ybr = 0.f, ybi = 0.f;
    if (hasB) {
        float2 b1 = make_float2(hbr*X1.x - hbi*X1.y, hbr*X1.y + hbi*X1.x);
        float2 b2 = make_float2(hbr2*X1.x + hbi2*X1.y, hbi2*X1.x - hbr2*X1.y);
        ybr = 0.5f*(b1.x + b2.x); ybi = 0.5f*(b1.y - b2.y);
    }
    Wk  = make_float2(yar - ybi, yai + ybr);
    WkL = make_float2(yar + ybi, ybr - yai);
}

// ---- fused Herm-build + 512-pt column FFT (in-place DIF, sign +1), 8 low + 8 mirror cols
// Block bb in [0,64): low cols {8bb..8bb+7} (slots 0-7), mirror cols {1024-8bb-s}
// (slots 8+s). Block 0: col 0 self-mirrored in slot 0, col 512 in slot 8.
// Reads H,X directly (no W buffer), writes D[jj*1024+truec] with four-step twiddle.
// LDS ~70 KB -> 2 blocks x 1024 threads / CU.
__global__ __launch_bounds__(1024) void kBW(const float* __restrict__ Hr,
                                            const float* __restrict__ Hi,
                                            const float2* __restrict__ X,
                                            float2* __restrict__ D1, int pair0) {
    __shared__ float sRe[16][513];
    __shared__ float sIm[16][513];
    __shared__ float2 twid[512];     // twid[h+q] = e^{+i pi q/h}
    int bb = blockIdx.x;             // column group 0..63
    int pl = blockIdx.y;             // pair within chunk
    int p  = pair0 + pl;
    int ca = 2*p, cb = 2*p + 1;
    bool hasB = (cb < NCH);
    const float* Har = Hr + (size_t)ca * LN;
    const float* Hai = Hi + (size_t)ca * LN;
    const float* Hbr = hasB ? (Hr + (size_t)cb * LN) : Har;
    const float* Hbi = hasB ? (Hi + (size_t)cb * LN) : Hai;
    float2* Dp = D1 + (size_t)pl * LN;
    unsigned c_base = 8u * bb;
    int t = threadIdx.x;

    if (t >= 1 && t < 512) {
        int h = 1 << (31 - __clz((unsigned)t));
        float ang = 3.14159265358979323846f * (float)(t - h) / (float)h;
        float s, c; __sincosf(ang, &s, &c);
        twid[t] = make_float2(c, s);
    }

    // ---- phase 1: Hermitian build of 16 columns (8 low + 8 mirror) into LDS ----
#pragma unroll
    for (int i = 0; i < 4; i++) {
        int e = t + (i << 10);
        unsigned s   = (unsigned)(e & 7);
        unsigned idx = (unsigned)(e >> 3);          // 0..511
        unsigned r = (idx & 0x1E0u) | ((idx & 3u) << 3) | ((idx >> 2) & 7u);
        if (bb == 0 && s == 0) {
            // col 0 (self-mirrored rows; bins 0 and L/2 special)
            if (r == 0 || r == 256) {
                unsigned k = 1024u * r;
                float2 Xv = X[k];
                float2 a1 = cmulf(make_float2(Har[k], Hai[k]), Xv);
                float br = 0.f;
                if (hasB) { float2 b1 = cmulf(make_float2(Hbr[k], Hbi[k]), Xv); br = b1.x; }
                sRe[0][r] = a1.x; sIm[0][r] = br;
            } else if (r < 256) {
                unsigned k = 1024u * r, kL = 1024u * (512 - r);
                float2 Wk, WkL;
                herm2(X[k], Har[k], Hai[k], Hbr[k], Hbi[k],
                      Har[kL], Hai[kL], Hbr[kL], Hbi[kL], hasB, Wk, WkL);
                sRe[0][r] = Wk.x;        sIm[0][r] = Wk.y;
                sRe[0][512 - r] = WkL.x; sIm[0][512 - r] = WkL.y;
            }
            if (r < 256) {   // col 512 -> slot 8 (self-mirrored: rows r <-> 511-r)
                unsigned k = 1024u * r + 512u, kL = 1024u * (511 - r) + 512u;
                float2 Wk, WkL;
                herm2(X[k], Har[k], Hai[k], Hbr[k], Hbi[k],
                      Har[kL], Hai[kL], Hbr[kL], Hbi[kL], hasB, Wk, WkL);
                sRe[8][r] = Wk.x;         sIm[8][r] = Wk.y;
                sRe[8][511 - r] = WkL.x;  sIm[8][511 - r] = WkL.y;
            }
        } else {
            unsigned c  = c_base + s;
            unsigned k  = 1024u * r + c;
            unsigned kL = 1024u * (511 - r) + (1024u - c);
            float2 Wk, WkL;
            herm2(X[k], Har[k], Hai[k], Hbr[k], Hbi[k],
                  Har[kL], Hai[kL], Hbr[kL], Hbi[kL], hasB, Wk, WkL);
            sRe[s][r] = Wk.x;                sIm[s][r] = Wk.y;
            sRe[8 + s][511 - r] = WkL.x;     sIm[8 + s][511 - r] = WkL.y;
        }
    }
    __syncthreads();

    // ---- phase 2: 9-stage in-place radix-2 DIF over rows, lane-fast over 16 cols ----
    int cc   = t & 15;
    int jgrp = t >> 4;               // 0..63
    for (int h = 256; h >= 1; h >>= 1) {
#pragma unroll
        for (int i = 0; i < 4; i++) {
            int j = jgrp + (i << 6);             // 0..255
            int q = j & (h - 1);
            int base = ((j & ~(h - 1)) << 1) | q;
            float2 w = twid[h + q];
            float are = sRe[cc][base],     aim = sIm[cc][base];
            float bre = sRe[cc][base + h], bim = sIm[cc][base + h];
            sRe[cc][base] = are + bre;  sIm[cc][base] = aim + bim;
            float dre = are - bre, dim = aim - bim;
            sRe[cc][base + h] = dre*w.x - dim*w.y;
            sIm[cc][base + h] = dre*w.y + dim*w.x;
        }
        __syncthreads();
    }

    // ---- phase 3: bitrev row, four-step twiddle, coalesced write D[jj][truec] ----
    const float c2pi = 6.28318530717958647692f / (float)LN;
    int slot = t & 15;
    unsigned truec = (slot < 8) ? (c_base + (unsigned)slot)
                   : ((bb == 0 && slot == 8) ? 512u
                                             : (1024u - c_base - (unsigned)(slot - 8)));
    int pos0 = t >> 4;               // 0..63
#pragma unroll
    for (int i = 0; i < 8; i++) {
        int pos = pos0 + (i << 6);               // 0..511
        unsigned jj = __brev((unsigned)pos) >> 23;   // bitrev9
        float re = sRe[slot][pos], im = sIm[slot][pos];
        unsigned prod = (jj * truec) & (unsigned)(LN - 1);
        float ang = c2pi * (float)prod;
        float s, c;
        __sincosf(ang, &s, &c);
        Dp[(size_t)jj * N2 + truec] = make_float2(re*c - im*s, re*s + im*c);
    }
}

// ---------------- final transpose of IFFT + 1/L scale + power-law (fast pow) ----------
__global__ void ifft_finish(const float2* __restrict__ src, float* __restrict__ comp,
                            const float* __restrict__ alpha_comp, int pair0) {
    __shared__ float2 tile[32][33];
    int pl = blockIdx.z;
    int p = pair0 + pl;
    int ca = 2*p, cb = 2*p + 1;
    const float2* s = src + (size_t)pl * LN;
    int x  = blockIdx.x * 32 + threadIdx.x;   // col (m) in [0,1024)
    int y0 = blockIdx.y * 32 + threadIdx.y;   // row (j) in [0,512)
#pragma unroll
    for (int i = 0; i < 32; i += 8)
        tile[threadIdx.y + i][threadIdx.x] = s[(size_t)(y0 + i) * N2 + x];
    __syncthreads();
    float aa = alpha_comp[ca];
    float ab = (cb < NCH) ? alpha_comp[cb] : 1.f;
    const float invL = 1.f / (float)LN;
    int xo  = blockIdx.y * 32 + threadIdx.x;  // j
    int yo0 = blockIdx.x * 32 + threadIdx.y;  // m
#pragma unroll
    for (int i = 0; i < 32; i += 8) {
        int yo = yo0 + i;
        float2 v = tile[threadIdx.x][threadIdx.y + i];
        size_t n = (size_t)yo * N1 + xo;      // n = 512*m + j
        float ra = v.x * invL;
        float rb = v.y * invL;
        comp[(size_t)ca * LN + n] = powsign(ra, aa);
        if (cb < NCH)
            comp[(size_t)cb * LN + n] = powsign(rb, ab);
    }
}

// ---------------- leaky IIR part 1: thread-per-20-samples + affine shuffle scan ----------
__global__ __launch_bounds__(256) void iir_part1(
    const float* __restrict__ comp, const float* __restrict__ alpha_leak,
    const float* __restrict__ li_kernel, float* __restrict__ out,
    float* __restrict__ carryOut) {
    __shared__ float win[SPB + SPB/TPW];   // pad every 20 (stride 21)
    __shared__ float wv[4], wg[4];
    int blk = blockIdx.x;
    int c = blockIdx.y;
    int t = threadIdx.x;
    float alpha = alpha_leak[0];
    float k0 = li_kernel[0], k1 = li_kernel[1];
    int base = blk * SPB;
    const int cap = NOUT * DSR;   // 524240
    const float* c0 = comp + (size_t)c * LN;
    const float* c1 = (c + 1 < NCH) ? comp + (size_t)(c + 1) * LN : nullptr;
    for (int i = t; i < SPB; i += 256) {
        int g = base + i;
        float v = 0.f;
        if (g < cap) {
            float u0 = c0[g];
            float u1 = c1 ? c1[g] : 0.f;
            v = fmaxf(k0 * u0 + k1 * u1, 0.f);
        }
        win[i + i / TPW] = v;
    }
    __syncthreads();
    float v = 0.f;
    int lbase = 21 * t;
#pragma unroll
    for (int i = 0; i < TPW; i++)
        v = fmaf(alpha, v, win[lbase + i]);
    float g = powf(alpha, (float)TPW);
    int lid = t & 63, wid = t >> 6;
#pragma unroll
    for (int d = 1; d < 64; d <<= 1) {
        float pv = __shfl_up(v, d);
        float pg = __shfl_up(g, d);
        if (lid >= d) { v = fmaf(g, pv, v); g = g * pg; }
    }
    if (lid == 63) { wv[wid] = v; wg[wid] = g; }
    __syncthreads();
    float cv = 0.f;
#pragma unroll
    for (int w = 0; w < 3; w++)
        if (w < wid) cv = wv[w] + wg[w] * cv;
    float vf = fmaf(g, cv, v);
    int nact = NOUT - blk * OB2; if (nact > OB2) nact = OB2;
    if ((t & 3) == 3) {
        int o = t >> 2;
        if (o < nact)
            out[(size_t)c * NOUT + blk * OB2 + o] = vf;
    }
    if (t == 4 * nact - 1)
        carryOut[c * NBLK + blk] = vf;
}

// ---------------- IIR part 2: per-channel carries (incl. circular wrap) ----------------
__global__ void iir_part2(const float* __restrict__ comp, const float* __restrict__ alpha_leak,
                          const float* __restrict__ li_kernel,
                          const float* __restrict__ carryOut, float* __restrict__ D) {
    int c = threadIdx.x;
    if (c >= NCH) return;
    float alpha = alpha_leak[0];
    float k0 = li_kernel[0], k1 = li_kernel[1];
    const float* c0 = comp + (size_t)c * LN;
    const float* c1 = (c + 1 < NCH) ? comp + (size_t)(c + 1) * LN : nullptr;
    float tail = 0.f, ap = 1.f;
    for (int j = 0; j < KTAIL; j++) {
        int g = LN - 1 - j;
        float u0 = c0[g];
        float u1 = c1 ? c1[g] : 0.f;
        float v = k0 * u0 + k1 * u1; v = v > 0.f ? v : 0.f;
        tail += ap * v;
        ap *= alpha;
    }
    float D0 = tail + ap * carryOut[c * NBLK + (NBLK - 1)]
             + powf(alpha, (float)(KTAIL + 2000)) * carryOut[c * NBLK + (NBLK - 2)];
    D[c * NBLK + 0] = D0;
    for (int b = 1; b < NBLK; b++)
        D[c * NBLK + b] = carryOut[c * NBLK + b - 1];
}

// ---------------- IIR part 3: add decayed carry into each output ----------------
__global__ void iir_part3(const float* __restrict__ D, const float* __restrict__ alpha_leak,
                          float* __restrict__ out) {
    int idx = blockIdx.x * 256 + threadIdx.x;
    if (idx >= NCH * NOUT) return;
    int c = idx / NOUT, m = idx - c * NOUT;
    int b = m / OB2, o = m - b * OB2;
    float alpha = alpha_leak[0];
    float beta = powf(alpha, (float)DSR);
    float dec = powf(beta, (float)(o + 1));
    out[idx] += dec * D[c * NBLK + b];
}

extern "C" void kernel_launch(void* const* d_in, const int* in_sizes, int n_in,
                              void* d_out, int out_size, void* d_ws, size_t ws_size,
                              hipStream_t stream) {
    const float* x  = (const float*)d_in[0];
    const float* Hr = (const float*)d_in[1];
    const float* Hi = (const float*)d_in[2];
    const float* ac = (const float*)d_in[3];
    const float* al = (const float*)d_in[4];
    const float* li = (const float*)d_in[5];
    float* out = (float*)d_out;

    char* ws = (char*)d_ws;
    size_t off = 0;
    auto alloc = [&](size_t bytes) -> void* {
        void* p = ws + off;
        off += (bytes + 255) & ~(size_t)255;
        return p;
    };
    float2* Xf     = (float2*)alloc((size_t)LN * sizeof(float2));
    float*  comp   = (float*) alloc((size_t)NCH * LN * sizeof(float));
    float*  cOut   = (float*) alloc((size_t)NCH * NBLK * sizeof(float));
    float*  Dbuf   = (float*) alloc((size_t)NCH * NBLK * sizeof(float));
    size_t remain = (ws_size > off) ? (ws_size - off) : 0;
    int chunk = (int)(remain / ((size_t)LN * sizeof(float2)));
    if (chunk > NPAIR) chunk = NPAIR;
    if (chunk < 2)     chunk = 2;
    float2* bufA = (float2*)alloc((size_t)chunk * LN * sizeof(float2));

    dim3 tb(32, 8, 1);

    // ---- forward FFT of x (four-step with transposes; small, one signal) ----
    float2* fA = bufA;
    float2* fB = bufA + LN;
    pack_x<<<LN / 256, 256, 0, stream>>>(x, fA);
    transpose_c<<<dim3(N2/32, N1/32, 1), tb, 0, stream>>>(fA, fB, N1, N2);
    fft_rows<N1, -1, 1><<<N2, 256, 0, stream>>>(fB, fB, N2);
    transpose_c<<<dim3(N1/32, N2/32, 1), tb, 0, stream>>>(fB, fA, N2, N1);
    fft_rows<N2, -1, 0><<<N1, 256, 0, stream>>>(fA, fA, N1);
    transpose_c<<<dim3(N2/32, N1/32, 1), tb, 0, stream>>>(fA, Xf, N1, N2);

    // ---- batched inverse FFTs: fused herm+colFFT -> rowFFT -> finish ----
    for (int ci = 0; ci < NPAIR; ci += chunk) {
        int np = NPAIR - ci; if (np > chunk) np = chunk;
        kBW<<<dim3(64, np), 1024, 0, stream>>>(Hr, Hi, Xf, bufA, ci);
        fft_rows<N2, 1, 0><<<N1 * np, 256, 0, stream>>>(bufA, bufA, N1);
        ifft_finish<<<dim3(N2/32, N1/32, np), tb, 0, stream>>>(bufA, comp, ac, ci);
    }

    // ---- leaky integration (time-domain, exact to fp precision) + downsample ----
    iir_part1<<<dim3(NBLK, NCH, 1), 256, 0, stream>>>(comp, al, li, out, cOut);
    iir_part2<<<1, 256, 0, stream>>>(comp, al, li, cOut, Dbuf);
    iir_part3<<<(NCH * NOUT + 255) / 256, 256, 0, stream>>>(Dbuf, al, out);
}

// Round 10
// 671.531 us; speedup vs baseline: 1.4082x; 1.4082x over previous
//
#include <hip/hip_runtime.h>
#include <math.h>

#define LN    524288        // signal length, 2^19
#define N1    512           // first-FFT length (column FFT)
#define N2    1024          // second-FFT length (row FFT)
#define NCH   129
#define DSR   80            // downsample rate
#define NOUT  6553          // output frames per channel
#define OB2   64            // outputs per IIR block
#define NBLK  103           // ceil(NOUT/OB2)
#define SPB   (OB2*DSR)     // 5120 samples per IIR block
#define TPW   20            // samples per thread in IIR
#define NPAIR 65            // ceil(129/2) channel pairs
#define KTAIL 48            // LN - NOUT*DSR
#define SB    1024          // build_w4 low-segment length per block
#define LMAP(i) ((i) + ((i) >> 3))   // LDS bank-spread map (2-way max)

__device__ __forceinline__ float2 cmulf(float2 a, float2 b) {
    return make_float2(a.x*b.x - a.y*b.y, a.x*b.y + a.y*b.x);
}

// fast |x|^a * sign(x): hardware log2/exp2 (x=0 -> -inf -> 0, correct)
__device__ __forceinline__ float powsign(float x, float a) {
    float m = __builtin_amdgcn_exp2f(a * __builtin_amdgcn_logf(fabsf(x)));
    return copysignf(m, x);
}

// ---------------- pack real x into complex buffer ----------------
__global__ void pack_x(const float* __restrict__ x, float2* __restrict__ dst) {
    int i = blockIdx.x * 256 + threadIdx.x;
    dst[i] = make_float2(x[i], 0.f);
}

// ---------------- tiled complex transpose (forward path only) ----------------
__global__ void transpose_c(const float2* __restrict__ src, float2* __restrict__ dst,
                            int R, int Cc) {
    __shared__ float2 tile[32][33];
    size_t boff = (size_t)blockIdx.z * LN;
    src += boff; dst += boff;
    int x  = blockIdx.x * 32 + threadIdx.x;
    int y0 = blockIdx.y * 32 + threadIdx.y;
#pragma unroll
    for (int i = 0; i < 32; i += 8)
        tile[threadIdx.y + i][threadIdx.x] = src[(size_t)(y0 + i) * Cc + x];
    __syncthreads();
    int xo  = blockIdx.y * 32 + threadIdx.x;
    int yo0 = blockIdx.x * 32 + threadIdx.y;
#pragma unroll
    for (int i = 0; i < 32; i += 8)
        dst[(size_t)(yo0 + i) * R + xo] = tile[threadIdx.x][threadIdx.y + i];
}

// ---------------- LDS Stockham radix-2 row FFT, float4 I/O, LDS twiddle table -----
template<int M, int SIGN, int TW>
__global__ __launch_bounds__(256) void fft_rows(const float2* __restrict__ src,
                                                float2* __restrict__ dst,
                                                int rows_per_batch) {
    __shared__ __align__(16) float2 ping[M];
    __shared__ __align__(16) float2 pong[M];
    __shared__ float2 twid[M];       // twid[Ns+jm] = e^{SIGN*i*pi*jm/Ns}
    size_t rowg = blockIdx.x;
    const float2* srow = src + rowg * M;
    float2* drow = dst + rowg * M;
    int row = (int)(rowg % (size_t)rows_per_batch);
    int t = threadIdx.x;
    const float4* s4 = (const float4*)srow;
    for (int ii = t; ii < M/2; ii += 256)
        *(float4*)&ping[2*ii] = s4[ii];
    for (int i = t; i < M; i += 256) {
        if (i >= 1) {
            int h = 1 << (31 - __clz((unsigned)i));
            float ang = (float)SIGN * 3.14159265358979323846f * (float)(i - h) / (float)h;
            float s, c; __sincosf(ang, &s, &c);
            twid[i] = make_float2(c, s);
        }
    }
    __syncthreads();
    float2* a = ping;
    float2* b = pong;
    for (int Ns = 1; Ns < M; Ns <<= 1) {
        for (int j = t; j < M/2; j += 256) {
            int jm = j & (Ns - 1);
            float2 v0 = a[j];
            float2 v1 = a[j + M/2];
            float2 tw = twid[Ns + jm];
            float2 w = make_float2(v1.x*tw.x - v1.y*tw.y, v1.x*tw.y + v1.y*tw.x);
            int d0 = ((j & ~(Ns - 1)) << 1) | jm;
            b[d0]      = make_float2(v0.x + w.x, v0.y + w.y);
            b[d0 + Ns] = make_float2(v0.x - w.x, v0.y - w.y);
        }
        __syncthreads();
        float2* tmp = a; a = b; b = tmp;
    }
    if (TW) {
        const float c2pi = 6.28318530717958647692f / (float)LN;
        for (int i = t; i < M; i += 256) {
            float2 v = a[i];
            unsigned prod = ((unsigned)row * (unsigned)i) & (unsigned)(LN - 1);
            float ang = (float)SIGN * c2pi * (float)prod;
            float s, c;
            __sincosf(ang, &s, &c);
            drow[i] = make_float2(v.x*c - v.y*s, v.x*s + v.y*c);
        }
    } else {
        float4* d4 = (float4*)drow;
        for (int ii = t; ii < M/2; ii += 256)
            d4[ii] = *(const float4*)&a[2*ii];
    }
}

// ---------------- Hermitian-combine W[k],W[L-k] from H,X (X real => X[L-k]=conj X[k]) ----
__device__ __forceinline__ void herm2(float2 X1,
                                      float har,  float hai,  float hbr,  float hbi,
                                      float har2, float hai2, float hbr2, float hbi2,
                                      bool hasB, float2& Wk, float2& WkL) {
    float2 a1 = make_float2(har*X1.x - hai*X1.y, har*X1.y + hai*X1.x);
    float2 a2 = make_float2(har2*X1.x + hai2*X1.y, hai2*X1.x - har2*X1.y);
    float yar = 0.5f*(a1.x + a2.x), yai = 0.5f*(a1.y - a2.y);
    float ybr = 0.f, ybi = 0.f;
    if (hasB) {
        float2 b1 = make_float2(hbr*X1.x - hbi*X1.y, hbr*X1.y + hbi*X1.x);
        float2 b2 = make_float2(hbr2*X1.x + hbi2*X1.y, hbi2*X1.x - hbr2*X1.y);
        ybr = 0.5f*(b1.x + b2.x); ybi = 0.5f*(b1.y - b2.y);
    }
    Wk  = make_float2(yar - ybi, yai + ybr);
    WkL = make_float2(yar + ybi, ybr - yai);
}

// ---- build_w4: LDS-staged Hermitian pairing, ALL global access aligned float4 ----
// Block stages low seg H[s0..s0+SB] and mirror seg H[L-s0-SB..L-s0] (incl. stragglers)
// into bank-spread LDS, then emits W low quad + W mirror quad per thread.
__global__ __launch_bounds__(256) void build_w4(const float* __restrict__ Hr,
                                                const float* __restrict__ Hi,
                                                const float2* __restrict__ X,
                                                float2* __restrict__ W, int pair0) {
    __shared__ float lowS[4][1160];
    __shared__ float mirS[4][1160];
    int s0 = blockIdx.x * SB;            // [0, LN/2)
    int pl = blockIdx.y;
    int p  = pair0 + pl;
    int ca = 2*p, cb = 2*p + 1;
    bool hasB = (cb < NCH);
    const float* Hs0 = Hr + (size_t)ca * LN;
    const float* Hs1 = Hi + (size_t)ca * LN;
    const float* Hs2 = hasB ? (Hr + (size_t)cb * LN) : Hs0;
    const float* Hs3 = hasB ? (Hi + (size_t)cb * LN) : Hs1;
    const float* Hs[4] = {Hs0, Hs1, Hs2, Hs3};
    float2* Wp = W + (size_t)pl * LN;
    int t = threadIdx.x;
    int j4 = 4 * t;
    int mbase = LN - s0 - SB;            // mirror segment start

    // ---- stage (aligned float4 reads; scalar bank-spread LDS writes) ----
#pragma unroll
    for (int a = 0; a < 4; a++) {
        float4 lv = *(const float4*)&Hs[a][s0 + j4];
        float4 mv = *(const float4*)&Hs[a][mbase + j4];
        int lm = LMAP(j4);
        lowS[a][lm+0] = lv.x; lowS[a][lm+1] = lv.y; lowS[a][lm+2] = lv.z; lowS[a][lm+3] = lv.w;
        mirS[a][lm+0] = mv.x; mirS[a][lm+1] = mv.y; mirS[a][lm+2] = mv.z; mirS[a][lm+3] = mv.w;
    }
    if (t == 0) {
#pragma unroll
        for (int a = 0; a < 4; a++) lowS[a][LMAP(SB)] = Hs[a][s0 + SB];
    }
    if (t == 1 && s0 > 0) {
#pragma unroll
        for (int a = 0; a < 4; a++) mirS[a][LMAP(SB)] = Hs[a][LN - s0];
    }
    __syncthreads();

    // ---- low quad: k = s0 + j4 + d ----
    float4 xa = *(const float4*)&X[s0 + j4];       // X[k], X[k+1]
    float4 xb = *(const float4*)&X[s0 + j4 + 2];   // X[k+2], X[k+3]
    float2 wlo[4];
#pragma unroll
    for (int d = 0; d < 4; d++) {
        int k = s0 + j4 + d;
        float2 Xk = (d == 0) ? make_float2(xa.x, xa.y) :
                    (d == 1) ? make_float2(xa.z, xa.w) :
                    (d == 2) ? make_float2(xb.x, xb.y) : make_float2(xb.z, xb.w);
        if (k == 0) {
            float2 Ya = cmulf(make_float2(lowS[0][0], lowS[1][0]), Xk);
            float br = 0.f;
            if (hasB) { float2 Yb = cmulf(make_float2(lowS[2][0], lowS[3][0]), Xk); br = Yb.x; }
            wlo[d] = make_float2(Ya.x, br);
        } else {
            int jl = LMAP(j4 + d);
            int jm = LMAP(SB - j4 - d);
            float2 Wk, WkL;
            herm2(Xk, lowS[0][jl], lowS[1][jl], lowS[2][jl], lowS[3][jl],
                      mirS[0][jm], mirS[1][jm], mirS[2][jm], mirS[3][jm], hasB, Wk, WkL);
            wlo[d] = Wk;
        }
    }
    *(float4*)&Wp[s0 + j4]     = make_float4(wlo[0].x, wlo[0].y, wlo[1].x, wlo[1].y);
    *(float4*)&Wp[s0 + j4 + 2] = make_float4(wlo[2].x, wlo[2].y, wlo[3].x, wlo[3].y);

    // ---- mirror quad: m = mbase + j4 + d  (m in (LN/2, LN) except the LN/2 bin) ----
    float2 wmi[4];
#pragma unroll
    for (int d = 0; d < 4; d++) {
        int m = mbase + j4 + d;
        if (m == LN/2) {
            float2 Xv = X[LN/2];
            float2 Ya = cmulf(make_float2(mirS[0][0], mirS[1][0]), Xv);
            float br = 0.f;
            if (hasB) { float2 Yb = cmulf(make_float2(mirS[2][0], mirS[3][0]), Xv); br = Yb.x; }
            wmi[d] = make_float2(Ya.x, br);
        } else {
            int kp = LN - m;                 // in (s0, s0+SB]
            int jl = LMAP(SB - j4 - d);      // low slot kp - s0
            int jm = LMAP(j4 + d);           // mirror slot m - mbase
            float2 Xk = X[kp];
            float2 Wk, WkL;
            herm2(Xk, lowS[0][jl], lowS[1][jl], lowS[2][jl], lowS[3][jl],
                      mirS[0][jm], mirS[1][jm], mirS[2][jm], mirS[3][jm], hasB, Wk, WkL);
            wmi[d] = WkL;
        }
    }
    *(float4*)&Wp[mbase + j4]     = make_float4(wmi[0].x, wmi[0].y, wmi[1].x, wmi[1].y);
    *(float4*)&Wp[mbase + j4 + 2] = make_float4(wmi[2].x, wmi[2].y, wmi[3].x, wmi[3].y);
}

// ---------------- column FFT: 16 consecutive cols per block, in-place DIF, sign +1 ----
__global__ __launch_bounds__(1024) void kB(float2* __restrict__ D1) {
    __shared__ float sRe[16][513];
    __shared__ float sIm[16][513];
    __shared__ float2 twid[512];     // twid[h+q] = e^{+i pi q/h}
    int cg = blockIdx.x;             // column group 0..63
    int pl = blockIdx.y;             // pair within chunk
    float2* Dp = D1 + (size_t)pl * LN;
    unsigned c_base = 16u * cg;
    int t = threadIdx.x;

    if (t >= 1 && t < 512) {
        int h = 1 << (31 - __clz((unsigned)t));
        float ang = 3.14159265358979323846f * (float)(t - h) / (float)h;
        float s, c; __sincosf(ang, &s, &c);
        twid[t] = make_float2(c, s);
    }

    // ---- phase 1: load 16 columns (128B segments; r perm spreads banks) ----
#pragma unroll
    for (int i = 0; i < 8; i++) {
        int e = t + (i << 10);
        unsigned c_off = (unsigned)(e & 15);
        unsigned idx   = (unsigned)(e >> 4);        // 0..511
        unsigned r = (idx & 0x1E0u) | ((idx & 3u) << 3) | ((idx >> 2) & 7u);
        float2 v = Dp[(size_t)r * N2 + c_base + c_off];
        sRe[c_off][r] = v.x;
        sIm[c_off][r] = v.y;
    }
    __syncthreads();

    // ---- phase 2: 9-stage in-place radix-2 DIF over rows, lane-fast over 16 cols ----
    int cc   = t & 15;
    int jgrp = t >> 4;               // 0..63
    for (int h = 256; h >= 1; h >>= 1) {
#pragma unroll
        for (int i = 0; i < 4; i++) {
            int j = jgrp + (i << 6);             // 0..255
            int q = j & (h - 1);
            int base = ((j & ~(h - 1)) << 1) | q;
            float2 w = twid[h + q];
            float are = sRe[cc][base],     aim = sIm[cc][base];
            float bre = sRe[cc][base + h], bim = sIm[cc][base + h];
            sRe[cc][base] = are + bre;  sIm[cc][base] = aim + bim;
            float dre = are - bre, dim = aim - bim;
            sRe[cc][base + h] = dre*w.x - dim*w.y;
            sIm[cc][base + h] = dre*w.y + dim*w.x;
        }
        __syncthreads();
    }

    // ---- phase 3: bitrev row, four-step twiddle, coalesced in-place write ----
    const float c2pi = 6.28318530717958647692f / (float)LN;
    unsigned truec = c_base + (unsigned)(t & 15);
    int pos0 = t >> 4;               // 0..63
#pragma unroll
    for (int i = 0; i < 8; i++) {
        int pos = pos0 + (i << 6);               // 0..511
        unsigned jj = __brev((unsigned)pos) >> 23;   // bitrev9
        float re = sRe[t & 15][pos], im = sIm[t & 15][pos];
        unsigned prod = (jj * truec) & (unsigned)(LN - 1);
        float ang = c2pi * (float)prod;
        float s, c;
        __sincosf(ang, &s, &c);
        Dp[(size_t)jj * N2 + truec] = make_float2(re*c - im*s, re*s + im*c);
    }
}

// ---------------- final transpose + 1/L scale + power-law, float4 in/out ----------
// block (8,32), grid (32 m-tiles, 16 j-tiles, np). n = m*512 + j.
__global__ __launch_bounds__(256) void ifft_finish(const float2* __restrict__ src,
                                                   float* __restrict__ comp,
                                                   const float* __restrict__ alpha_comp,
                                                   int pair0) {
    __shared__ __align__(16) float2 tile[32][33];   // tile[j][m]
    int pl = blockIdx.z;
    int p = pair0 + pl;
    int ca = 2*p, cb = 2*p + 1;
    const float2* s = src + (size_t)pl * LN;
    int m0 = blockIdx.x * 32, j0 = blockIdx.y * 32;
    int tx = threadIdx.x, ty = threadIdx.y;
    int tid = ty * 8 + tx;
    int jl = tid >> 3, mq = tid & 7;
    const float4* row4 = (const float4*)&s[(size_t)(j0 + jl) * N2 + m0 + mq * 4];
    float4 a = row4[0], b = row4[1];
    tile[jl][mq*4+0] = make_float2(a.x, a.y);
    tile[jl][mq*4+1] = make_float2(a.z, a.w);
    tile[jl][mq*4+2] = make_float2(b.x, b.y);
    tile[jl][mq*4+3] = make_float2(b.z, b.w);
    __syncthreads();
    float aa = alpha_comp[ca];
    float ab = (cb < NCH) ? alpha_comp[cb] : 1.f;
    const float invL = 1.f / (float)LN;
    float oa[4], ob[4];
#pragma unroll
    for (int d = 0; d < 4; d++) {
        float2 v = tile[4*tx + d][ty];
        oa[d] = powsign(v.x * invL, aa);
        ob[d] = powsign(v.y * invL, ab);
    }
    size_t n0 = (size_t)(m0 + ty) * N1 + j0 + 4*tx;
    *(float4*)&comp[(size_t)ca * LN + n0] = make_float4(oa[0], oa[1], oa[2], oa[3]);
    if (cb < NCH)
        *(float4*)&comp[(size_t)cb * LN + n0] = make_float4(ob[0], ob[1], ob[2], ob[3]);
}

// ---------------- leaky IIR part 1: thread-per-20-samples + affine shuffle scan ----------
__global__ __launch_bounds__(256) void iir_part1(
    const float* __restrict__ comp, const float* __restrict__ alpha_leak,
    const float* __restrict__ li_kernel, float* __restrict__ out,
    float* __restrict__ carryOut) {
    __shared__ float win[SPB + SPB/TPW];   // pad every 20 (stride 21)
    __shared__ float wv[4], wg[4];
    int blk = blockIdx.x;
    int c = blockIdx.y;
    int t = threadIdx.x;
    float alpha = alpha_leak[0];
    float k0 = li_kernel[0], k1 = li_kernel[1];
    int base = blk * SPB;
    const int cap = NOUT * DSR;   // 524240
    const float* c0 = comp + (size_t)c * LN;
    const float* c1 = (c + 1 < NCH) ? comp + (size_t)(c + 1) * LN : nullptr;
    const float4 z4 = make_float4(0.f, 0.f, 0.f, 0.f);
    for (int i4 = 4*t; i4 < SPB; i4 += 1024) {
        int g = base + i4;
        float4 u0 = *(const float4*)&c0[g];
        float4 u1 = c1 ? *(const float4*)&c1[g] : z4;
        float vv[4] = {k0*u0.x + k1*u1.x, k0*u0.y + k1*u1.y,
                       k0*u0.z + k1*u1.z, k0*u0.w + k1*u1.w};
#pragma unroll
        for (int d = 0; d < 4; d++) {
            float v = fmaxf(vv[d], 0.f);
            if (g + d >= cap) v = 0.f;
            int i = i4 + d;
            win[i + i / TPW] = v;
        }
    }
    __syncthreads();
    float v = 0.f;
    int lbase = 21 * t;
#pragma unroll
    for (int i = 0; i < TPW; i++)
        v = fmaf(alpha, v, win[lbase + i]);
    float g = powf(alpha, (float)TPW);
    int lid = t & 63, wid = t >> 6;
#pragma unroll
    for (int d = 1; d < 64; d <<= 1) {
        float pv = __shfl_up(v, d);
        float pg = __shfl_up(g, d);
        if (lid >= d) { v = fmaf(g, pv, v); g = g * pg; }
    }
    if (lid == 63) { wv[wid] = v; wg[wid] = g; }
    __syncthreads();
    float cv = 0.f;
#pragma unroll
    for (int w = 0; w < 3; w++)
        if (w < wid) cv = wv[w] + wg[w] * cv;
    float vf = fmaf(g, cv, v);
    int nact = NOUT - blk * OB2; if (nact > OB2) nact = OB2;
    if ((t & 3) == 3) {
        int o = t >> 2;
        if (o < nact)
            out[(size_t)c * NOUT + blk * OB2 + o] = vf;
    }
    if (t == 4 * nact - 1)
        carryOut[c * NBLK + blk] = vf;
}

// ---------------- IIR part 2: per-channel carries (incl. circular wrap) ----------------
__global__ void iir_part2(const float* __restrict__ comp, const float* __restrict__ alpha_leak,
                          const float* __restrict__ li_kernel,
                          const float* __restrict__ carryOut, float* __restrict__ D) {
    int c = threadIdx.x;
    if (c >= NCH) return;
    float alpha = alpha_leak[0];
    float k0 = li_kernel[0], k1 = li_kernel[1];
    const float* c0 = comp + (size_t)c * LN;
    const float* c1 = (c + 1 < NCH) ? comp + (size_t)(c + 1) * LN : nullptr;
    float tail = 0.f, ap = 1.f;
    for (int j = 0; j < KTAIL; j++) {
        int g = LN - 1 - j;
        float u0 = c0[g];
        float u1 = c1 ? c1[g] : 0.f;
        float v = k0 * u0 + k1 * u1; v = v > 0.f ? v : 0.f;
        tail += ap * v;
        ap *= alpha;
    }
    float D0 = tail + ap * carryOut[c * NBLK + (NBLK - 1)]
             + powf(alpha, (float)(KTAIL + 2000)) * carryOut[c * NBLK + (NBLK - 2)];
    D[c * NBLK + 0] = D0;
    for (int b = 1; b < NBLK; b++)
        D[c * NBLK + b] = carryOut[c * NBLK + b - 1];
}

// ---------------- IIR part 3: add decayed carry into each output ----------------
__global__ void iir_part3(const float* __restrict__ D, const float* __restrict__ alpha_leak,
                          float* __restrict__ out) {
    int idx = blockIdx.x * 256 + threadIdx.x;
    if (idx >= NCH * NOUT) return;
    int c = idx / NOUT, m = idx - c * NOUT;
    int b = m / OB2, o = m - b * OB2;
    float alpha = alpha_leak[0];
    float beta = powf(alpha, (float)DSR);
    float dec = powf(beta, (float)(o + 1));
    out[idx] += dec * D[c * NBLK + b];
}

extern "C" void kernel_launch(void* const* d_in, const int* in_sizes, int n_in,
                              void* d_out, int out_size, void* d_ws, size_t ws_size,
                              hipStream_t stream) {
    const float* x  = (const float*)d_in[0];
    const float* Hr = (const float*)d_in[1];
    const float* Hi = (const float*)d_in[2];
    const float* ac = (const float*)d_in[3];
    const float* al = (const float*)d_in[4];
    const float* li = (const float*)d_in[5];
    float* out = (float*)d_out;

    char* ws = (char*)d_ws;
    size_t off = 0;
    auto alloc = [&](size_t bytes) -> void* {
        void* p = ws + off;
        off += (bytes + 255) & ~(size_t)255;
        return p;
    };
    float2* Xf     = (float2*)alloc((size_t)LN * sizeof(float2));
    float*  comp   = (float*) alloc((size_t)NCH * LN * sizeof(float));
    float*  cOut   = (float*) alloc((size_t)NCH * NBLK * sizeof(float));
    float*  Dbuf   = (float*) alloc((size_t)NCH * NBLK * sizeof(float));
    size_t remain = (ws_size > off) ? (ws_size - off) : 0;
    int chunk = (int)(remain / ((size_t)LN * sizeof(float2)));
    if (chunk > NPAIR) chunk = NPAIR;
    if (chunk < 2)     chunk = 2;
    float2* bufA = (float2*)alloc((size_t)chunk * LN * sizeof(float2));

    dim3 tb(32, 8, 1);

    // ---- forward FFT of x (four-step with transposes; small, one signal) ----
    float2* fA = bufA;
    float2* fB = bufA + LN;
    pack_x<<<LN / 256, 256, 0, stream>>>(x, fA);
    transpose_c<<<dim3(N2/32, N1/32, 1), tb, 0, stream>>>(fA, fB, N1, N2);
    fft_rows<N1, -1, 1><<<N2, 256, 0, stream>>>(fB, fB, N2);
    transpose_c<<<dim3(N1/32, N2/32, 1), tb, 0, stream>>>(fB, fA, N2, N1);
    fft_rows<N2, -1, 0><<<N1, 256, 0, stream>>>(fA, fA, N1);
    transpose_c<<<dim3(N2/32, N1/32, 1), tb, 0, stream>>>(fA, Xf, N1, N2);

    // ---- batched inverse FFTs: build_w4 -> colFFT(in-place) -> rowFFT -> finish ----
    for (int ci = 0; ci < NPAIR; ci += chunk) {
        int np = NPAIR - ci; if (np > chunk) np = chunk;
        build_w4<<<dim3(LN/2/SB, np), 256, 0, stream>>>(Hr, Hi, Xf, bufA, ci);
        kB<<<dim3(64, np), 1024, 0, stream>>>(bufA);
        fft_rows<N2, 1, 0><<<N1 * np, 256, 0, stream>>>(bufA, bufA, N1);
        ifft_finish<<<dim3(32, 16, np), dim3(8, 32), 0, stream>>>(bufA, comp, ac, ci);
    }

    // ---- leaky integration (time-domain, exact to fp precision) + downsample ----
    iir_part1<<<dim3(NBLK, NCH, 1), 256, 0, stream>>>(comp, al, li, out, cOut);
    iir_part2<<<1, 256, 0, stream>>>(comp, al, li, cOut, Dbuf);
    iir_part3<<<(NCH * NOUT + 255) / 256, 256, 0, stream>>>(Dbuf, al, out);
}

// Round 13
// 665.430 us; speedup vs baseline: 1.4211x; 1.0092x over previous
//
#include <hip/hip_runtime.h>
#include <math.h>

#define LN    524288        // signal length, 2^19
#define N1    512           // first-FFT length (column FFT)
#define N2    1024          // second-FFT length (row FFT)
#define NCH   129
#define DSR   80            // downsample rate
#define NOUT  6553          // output frames per channel
#define OB2   64            // outputs per IIR block
#define NBLK  103           // ceil(NOUT/OB2)
#define SPB   (OB2*DSR)     // 5120 samples per IIR block
#define TPW   20            // samples per thread in IIR
#define NPAIR 65            // ceil(129/2) channel pairs
#define KTAIL 48            // LN - NOUT*DSR
#define SB    1024          // build_w4 low-segment length per block
#define LMAP(i) ((i) + ((i) >> 3))   // LDS bank-spread map (2-way max)
#define SWZ(p)  ((p) ^ ((((p) >> 5) & 1) * 31))   // kB bank swizzle (2-way max, all h)

__device__ __forceinline__ float2 cmulf(float2 a, float2 b) {
    return make_float2(a.x*b.x - a.y*b.y, a.x*b.y + a.y*b.x);
}

// fast |x|^a * sign(x): hardware log2/exp2 (x=0 -> -inf -> 0, correct)
__device__ __forceinline__ float powsign(float x, float a) {
    float m = __builtin_amdgcn_exp2f(a * __builtin_amdgcn_logf(fabsf(x)));
    return copysignf(m, x);
}

// ---------------- pack real x into complex buffer ----------------
__global__ void pack_x(const float* __restrict__ x, float2* __restrict__ dst) {
    int i = blockIdx.x * 256 + threadIdx.x;
    dst[i] = make_float2(x[i], 0.f);
}

// ---------------- tiled complex transpose (forward path only) ----------------
__global__ void transpose_c(const float2* __restrict__ src, float2* __restrict__ dst,
                            int R, int Cc) {
    __shared__ float2 tile[32][33];
    size_t boff = (size_t)blockIdx.z * LN;
    src += boff; dst += boff;
    int x  = blockIdx.x * 32 + threadIdx.x;
    int y0 = blockIdx.y * 32 + threadIdx.y;
#pragma unroll
    for (int i = 0; i < 32; i += 8)
        tile[threadIdx.y + i][threadIdx.x] = src[(size_t)(y0 + i) * Cc + x];
    __syncthreads();
    int xo  = blockIdx.y * 32 + threadIdx.x;
    int yo0 = blockIdx.x * 32 + threadIdx.y;
#pragma unroll
    for (int i = 0; i < 32; i += 8)
        dst[(size_t)(yo0 + i) * R + xo] = tile[threadIdx.x][threadIdx.y + i];
}

// ---------------- LDS Stockham radix-2 row FFT, float4 I/O, LDS twiddle table -----
template<int M, int SIGN, int TW>
__global__ __launch_bounds__(256) void fft_rows(const float2* __restrict__ src,
                                                float2* __restrict__ dst,
                                                int rows_per_batch) {
    __shared__ __align__(16) float2 ping[M];
    __shared__ __align__(16) float2 pong[M];
    __shared__ float2 twid[M];       // twid[Ns+jm] = e^{SIGN*i*pi*jm/Ns}
    size_t rowg = blockIdx.x;
    const float2* srow = src + rowg * M;
    float2* drow = dst + rowg * M;
    int row = (int)(rowg % (size_t)rows_per_batch);
    int t = threadIdx.x;
    const float4* s4 = (const float4*)srow;
    for (int ii = t; ii < M/2; ii += 256)
        *(float4*)&ping[2*ii] = s4[ii];
    for (int i = t; i < M; i += 256) {
        if (i >= 1) {
            int h = 1 << (31 - __clz((unsigned)i));
            float ang = (float)SIGN * 3.14159265358979323846f * (float)(i - h) / (float)h;
            float s, c; __sincosf(ang, &s, &c);
            twid[i] = make_float2(c, s);
        }
    }
    __syncthreads();
    float2* a = ping;
    float2* b = pong;
    for (int Ns = 1; Ns < M; Ns <<= 1) {
        for (int j = t; j < M/2; j += 256) {
            int jm = j & (Ns - 1);
            float2 v0 = a[j];
            float2 v1 = a[j + M/2];
            float2 tw = twid[Ns + jm];
            float2 w = make_float2(v1.x*tw.x - v1.y*tw.y, v1.x*tw.y + v1.y*tw.x);
            int d0 = ((j & ~(Ns - 1)) << 1) | jm;
            b[d0]      = make_float2(v0.x + w.x, v0.y + w.y);
            b[d0 + Ns] = make_float2(v0.x - w.x, v0.y - w.y);
        }
        __syncthreads();
        float2* tmp = a; a = b; b = tmp;
    }
    if (TW) {
        const float c2pi = 6.28318530717958647692f / (float)LN;
        for (int i = t; i < M; i += 256) {
            float2 v = a[i];
            unsigned prod = ((unsigned)row * (unsigned)i) & (unsigned)(LN - 1);
            float ang = (float)SIGN * c2pi * (float)prod;
            float s, c;
            __sincosf(ang, &s, &c);
            drow[i] = make_float2(v.x*c - v.y*s, v.x*s + v.y*c);
        }
    } else {
        float4* d4 = (float4*)drow;
        for (int ii = t; ii < M/2; ii += 256)
            d4[ii] = *(const float4*)&a[2*ii];
    }
}

// ---------------- Hermitian-combine W[k],W[L-k] from H,X (X real => X[L-k]=conj X[k]) ----
__device__ __forceinline__ void herm2(float2 X1,
                                      float har,  float hai,  float hbr,  float hbi,
                                      float har2, float hai2, float hbr2, float hbi2,
                                      bool hasB, float2& Wk, float2& WkL) {
    float2 a1 = make_float2(har*X1.x - hai*X1.y, har*X1.y + hai*X1.x);
    float2 a2 = make_float2(har2*X1.x + hai2*X1.y, hai2*X1.x - har2*X1.y);
    float yar = 0.5f*(a1.x + a2.x), yai = 0.5f*(a1.y - a2.y);
    float ybr = 0.f, ybi = 0.f;
    if (hasB) {
        float2 b1 = make_float2(hbr*X1.x - hbi*X1.y, hbr*X1.y + hbi*X1.x);
        float2 b2 = make_float2(hbr2*X1.x + hbi2*X1.y, hbi2*X1.x - hbr2*X1.y);
        ybr = 0.5f*(b1.x + b2.x); ybi = 0.5f*(b1.y - b2.y);
    }
    Wk  = make_float2(yar - ybi, yai + ybr);
    WkL = make_float2(yar + ybi, ybr - yai);
}

// ---- build_w4: LDS-staged Hermitian pairing, ALL global access aligned float4 ----
__global__ __launch_bounds__(256) void build_w4(const float* __restrict__ Hr,
                                                const float* __restrict__ Hi,
                                                const float2* __restrict__ X,
                                                float2* __restrict__ W, int pair0) {
    __shared__ float lowS[4][1160];
    __shared__ float mirS[4][1160];
    int s0 = blockIdx.x * SB;            // [0, LN/2)
    int pl = blockIdx.y;
    int p  = pair0 + pl;
    int ca = 2*p, cb = 2*p + 1;
    bool hasB = (cb < NCH);
    const float* Hs0 = Hr + (size_t)ca * LN;
    const float* Hs1 = Hi + (size_t)ca * LN;
    const float* Hs2 = hasB ? (Hr + (size_t)cb * LN) : Hs0;
    const float* Hs3 = hasB ? (Hi + (size_t)cb * LN) : Hs1;
    const float* Hs[4] = {Hs0, Hs1, Hs2, Hs3};
    float2* Wp = W + (size_t)pl * LN;
    int t = threadIdx.x;
    int j4 = 4 * t;
    int mbase = LN - s0 - SB;            // mirror segment start

#pragma unroll
    for (int a = 0; a < 4; a++) {
        float4 lv = *(const float4*)&Hs[a][s0 + j4];
        float4 mv = *(const float4*)&Hs[a][mbase + j4];
        int lm = LMAP(j4);
        lowS[a][lm+0] = lv.x; lowS[a][lm+1] = lv.y; lowS[a][lm+2] = lv.z; lowS[a][lm+3] = lv.w;
        mirS[a][lm+0] = mv.x; mirS[a][lm+1] = mv.y; mirS[a][lm+2] = mv.z; mirS[a][lm+3] = mv.w;
    }
    if (t == 0) {
#pragma unroll
        for (int a = 0; a < 4; a++) lowS[a][LMAP(SB)] = Hs[a][s0 + SB];
    }
    if (t == 1 && s0 > 0) {
#pragma unroll
        for (int a = 0; a < 4; a++) mirS[a][LMAP(SB)] = Hs[a][LN - s0];
    }
    __syncthreads();

    float4 xa = *(const float4*)&X[s0 + j4];
    float4 xb = *(const float4*)&X[s0 + j4 + 2];
    float2 wlo[4];
#pragma unroll
    for (int d = 0; d < 4; d++) {
        int k = s0 + j4 + d;
        float2 Xk = (d == 0) ? make_float2(xa.x, xa.y) :
                    (d == 1) ? make_float2(xa.z, xa.w) :
                    (d == 2) ? make_float2(xb.x, xb.y) : make_float2(xb.z, xb.w);
        if (k == 0) {
            float2 Ya = cmulf(make_float2(lowS[0][0], lowS[1][0]), Xk);
            float br = 0.f;
            if (hasB) { float2 Yb = cmulf(make_float2(lowS[2][0], lowS[3][0]), Xk); br = Yb.x; }
            wlo[d] = make_float2(Ya.x, br);
        } else {
            int jl = LMAP(j4 + d);
            int jm = LMAP(SB - j4 - d);
            float2 Wk, WkL;
            herm2(Xk, lowS[0][jl], lowS[1][jl], lowS[2][jl], lowS[3][jl],
                      mirS[0][jm], mirS[1][jm], mirS[2][jm], mirS[3][jm], hasB, Wk, WkL);
            wlo[d] = Wk;
        }
    }
    *(float4*)&Wp[s0 + j4]     = make_float4(wlo[0].x, wlo[0].y, wlo[1].x, wlo[1].y);
    *(float4*)&Wp[s0 + j4 + 2] = make_float4(wlo[2].x, wlo[2].y, wlo[3].x, wlo[3].y);

    float2 wmi[4];
#pragma unroll
    for (int d = 0; d < 4; d++) {
        int m = mbase + j4 + d;
        if (m == LN/2) {
            float2 Xv = X[LN/2];
            float2 Ya = cmulf(make_float2(mirS[0][0], mirS[1][0]), Xv);
            float br = 0.f;
            if (hasB) { float2 Yb = cmulf(make_float2(mirS[2][0], mirS[3][0]), Xv); br = Yb.x; }
            wmi[d] = make_float2(Ya.x, br);
        } else {
            int kp = LN - m;                 // in (s0, s0+SB]
            int jl = LMAP(SB - j4 - d);      // low slot kp - s0
            int jm = LMAP(j4 + d);           // mirror slot m - mbase
            float2 Xk = X[kp];
            float2 Wk, WkL;
            herm2(Xk, lowS[0][jl], lowS[1][jl], lowS[2][jl], lowS[3][jl],
                      mirS[0][jm], mirS[1][jm], mirS[2][jm], mirS[3][jm], hasB, Wk, WkL);
            wmi[d] = WkL;
        }
    }
    *(float4*)&Wp[mbase + j4]     = make_float4(wmi[0].x, wmi[0].y, wmi[1].x, wmi[1].y);
    *(float4*)&Wp[mbase + j4 + 2] = make_float4(wmi[2].x, wmi[2].y, wmi[3].x, wmi[3].y);
}

// ---------------- column FFT: 16 cols/block, in-place DIF, sign +1, swizzled LDS ----
// LDS layout: sRe[cc][SWZ(pos)], stride 545 (=1 mod 32) -> bank = (cc + SWZ(pos)) % 32.
// Phase 2: one wave per column (cc wave-uniform), lanes sweep 64 consecutive j ->
// every stage h is exactly 2-way (free). Phases 1/3: row groups r = w+16g+64i give
// swizzle offsets {w, w+16, 31-w, 15-w} -> exact 2-way; global stays 4x128B segments.
__global__ __launch_bounds__(1024) void kB(float2* __restrict__ D1) {
    __shared__ float sRe[16][545];
    __shared__ float sIm[16][545];
    __shared__ float2 twid[512];     // twid[h+q] = e^{+i pi q/h}
    int cg = blockIdx.x;             // column group 0..63
    int pl = blockIdx.y;             // pair within chunk
    float2* Dp = D1 + (size_t)pl * LN;
    unsigned c_base = 16u * cg;
    int t = threadIdx.x;

    if (t >= 1 && t < 512) {
        int h = 1 << (31 - __clz((unsigned)t));
        float ang = 3.14159265358979323846f * (float)(t - h) / (float)h;
        float s, c; __sincosf(ang, &s, &c);
        twid[t] = make_float2(c, s);
    }

    int cc = t & 15;
    int g  = (t >> 4) & 3;
    int w  = t >> 6;

    // ---- phase 1: load 16 columns; rows r = w + 16g + 64i ----
#pragma unroll
    for (int i = 0; i < 8; i++) {
        int r = w + (g << 4) + (i << 6);
        float2 v = Dp[(size_t)r * N2 + c_base + cc];
        int sp = SWZ(r);
        sRe[cc][sp] = v.x;
        sIm[cc][sp] = v.y;
    }
    __syncthreads();

    // ---- phase 2: 9-stage in-place radix-2 DIF; wave = column, lanes = j ----
    int cc2 = t >> 6;                // 0..15 (wave-uniform)
    int l   = t & 63;
    for (int h = 256; h >= 1; h >>= 1) {
#pragma unroll
        for (int i = 0; i < 4; i++) {
            int j = l + (i << 6);                // 0..255
            int q = j & (h - 1);
            int base = ((j & ~(h - 1)) << 1) | q;
            float2 tw = twid[h + q];
            int p0 = SWZ(base), p1 = SWZ(base + h);
            float are = sRe[cc2][p0], aim = sIm[cc2][p0];
            float bre = sRe[cc2][p1], bim = sIm[cc2][p1];
            sRe[cc2][p0] = are + bre;  sIm[cc2][p0] = aim + bim;
            float dre = are - bre, dim = aim - bim;
            sRe[cc2][p1] = dre*tw.x - dim*tw.y;
            sIm[cc2][p1] = dre*tw.y + dim*tw.x;
        }
        __syncthreads();
    }

    // ---- phase 3: bitrev row, four-step twiddle, coalesced in-place write ----
    const float c2pi = 6.28318530717958647692f / (float)LN;
    unsigned truec = c_base + (unsigned)cc;
#pragma unroll
    for (int i = 0; i < 8; i++) {
        int pos = w + (g << 4) + (i << 6);           // 0..511
        unsigned jj = __brev((unsigned)pos) >> 23;   // bitrev9
        int sp = SWZ(pos);
        float re = sRe[cc][sp], im = sIm[cc][sp];
        unsigned prod = (jj * truec) & (unsigned)(LN - 1);
        float ang = c2pi * (float)prod;
        float s, c;
        __sincosf(ang, &s, &c);
        Dp[(size_t)jj * N2 + truec] = make_float2(re*c - im*s, re*s + im*c);
    }
}

// ---------------- final transpose + 1/L scale + power-law, float4 in/out ----------
__global__ __launch_bounds__(256) void ifft_finish(const float2* __restrict__ src,
                                                   float* __restrict__ comp,
                                                   const float* __restrict__ alpha_comp,
                                                   int pair0) {
    __shared__ __align__(16) float2 tile[32][33];   // tile[j][m]
    int pl = blockIdx.z;
    int p = pair0 + pl;
    int ca = 2*p, cb = 2*p + 1;
    const float2* s = src + (size_t)pl * LN;
    int m0 = blockIdx.x * 32, j0 = blockIdx.y * 32;
    int tx = threadIdx.x, ty = threadIdx.y;
    int tid = ty * 8 + tx;
    int jl = tid >> 3, mq = tid & 7;
    const float4* row4 = (const float4*)&s[(size_t)(j0 + jl) * N2 + m0 + mq * 4];
    float4 a = row4[0], b = row4[1];
    tile[jl][mq*4+0] = make_float2(a.x, a.y);
    tile[jl][mq*4+1] = make_float2(a.z, a.w);
    tile[jl][mq*4+2] = make_float2(b.x, b.y);
    tile[jl][mq*4+3] = make_float2(b.z, b.w);
    __syncthreads();
    float aa = alpha_comp[ca];
    float ab = (cb < NCH) ? alpha_comp[cb] : 1.f;
    const float invL = 1.f / (float)LN;
    float oa[4], ob[4];
#pragma unroll
    for (int d = 0; d < 4; d++) {
        float2 v = tile[4*tx + d][ty];
        oa[d] = powsign(v.x * invL, aa);
        ob[d] = powsign(v.y * invL, ab);
    }
    size_t n0 = (size_t)(m0 + ty) * N1 + j0 + 4*tx;
    *(float4*)&comp[(size_t)ca * LN + n0] = make_float4(oa[0], oa[1], oa[2], oa[3]);
    if (cb < NCH)
        *(float4*)&comp[(size_t)cb * LN + n0] = make_float4(ob[0], ob[1], ob[2], ob[3]);
}

// ---------------- leaky IIR part 1: thread-per-20-samples + affine shuffle scan ----------
__global__ __launch_bounds__(256) void iir_part1(
    const float* __restrict__ comp, const float* __restrict__ alpha_leak,
    const float* __restrict__ li_kernel, float* __restrict__ out,
    float* __restrict__ carryOut) {
    __shared__ float win[SPB + SPB/TPW];   // pad every 20 (stride 21)
    __shared__ float wv[4], wg[4];
    int blk = blockIdx.x;
    int c = blockIdx.y;
    int t = threadIdx.x;
    float alpha = alpha_leak[0];
    float k0 = li_kernel[0], k1 = li_kernel[1];
    int base = blk * SPB;
    const int cap = NOUT * DSR;   // 524240
    const float* c0 = comp + (size_t)c * LN;
    const float* c1 = (c + 1 < NCH) ? comp + (size_t)(c + 1) * LN : nullptr;
    const float4 z4 = make_float4(0.f, 0.f, 0.f, 0.f);
    for (int i4 = 4*t; i4 < SPB; i4 += 1024) {
        int g = base + i4;
        float4 u0 = *(const float4*)&c0[g];
        float4 u1 = c1 ? *(const float4*)&c1[g] : z4;
        float vv[4] = {k0*u0.x + k1*u1.x, k0*u0.y + k1*u1.y,
                       k0*u0.z + k1*u1.z, k0*u0.w + k1*u1.w};
#pragma unroll
        for (int d = 0; d < 4; d++) {
            float v = fmaxf(vv[d], 0.f);
            if (g + d >= cap) v = 0.f;
            int i = i4 + d;
            win[i + i / TPW] = v;
        }
    }
    __syncthreads();
    float v = 0.f;
    int lbase = 21 * t;
#pragma unroll
    for (int i = 0; i < TPW; i++)
        v = fmaf(alpha, v, win[lbase + i]);
    float g = powf(alpha, (float)TPW);
    int lid = t & 63, wid = t >> 6;
#pragma unroll
    for (int d = 1; d < 64; d <<= 1) {
        float pv = __shfl_up(v, d);
        float pg = __shfl_up(g, d);
        if (lid >= d) { v = fmaf(g, pv, v); g = g * pg; }
    }
    if (lid == 63) { wv[wid] = v; wg[wid] = g; }
    __syncthreads();
    float cv = 0.f;
#pragma unroll
    for (int w = 0; w < 3; w++)
        if (w < wid) cv = wv[w] + wg[w] * cv;
    float vf = fmaf(g, cv, v);
    int nact = NOUT - blk * OB2; if (nact > OB2) nact = OB2;
    if ((t & 3) == 3) {
        int o = t >> 2;
        if (o < nact)
            out[(size_t)c * NOUT + blk * OB2 + o] = vf;
    }
    if (t == 4 * nact - 1)
        carryOut[c * NBLK + blk] = vf;
}

// ---------------- IIR part 2: per-channel carries (incl. circular wrap) ----------------
__global__ void iir_part2(const float* __restrict__ comp, const float* __restrict__ alpha_leak,
                          const float* __restrict__ li_kernel,
                          const float* __restrict__ carryOut, float* __restrict__ D) {
    int c = threadIdx.x;
    if (c >= NCH) return;
    float alpha = alpha_leak[0];
    float k0 = li_kernel[0], k1 = li_kernel[1];
    const float* c0 = comp + (size_t)c * LN;
    const float* c1 = (c + 1 < NCH) ? comp + (size_t)(c + 1) * LN : nullptr;
    float tail = 0.f, ap = 1.f;
    for (int j = 0; j < KTAIL; j++) {
        int g = LN - 1 - j;
        float u0 = c0[g];
        float u1 = c1 ? c1[g] : 0.f;
        float v = k0 * u0 + k1 * u1; v = v > 0.f ? v : 0.f;
        tail += ap * v;
        ap *= alpha;
    }
    float D0 = tail + ap * carryOut[c * NBLK + (NBLK - 1)]
             + powf(alpha, (float)(KTAIL + 2000)) * carryOut[c * NBLK + (NBLK - 2)];
    D[c * NBLK + 0] = D0;
    for (int b = 1; b < NBLK; b++)
        D[c * NBLK + b] = carryOut[c * NBLK + b - 1];
}

// ---------------- IIR part 3: add decayed carry into each output ----------------
__global__ void iir_part3(const float* __restrict__ D, const float* __restrict__ alpha_leak,
                          float* __restrict__ out) {
    int idx = blockIdx.x * 256 + threadIdx.x;
    if (idx >= NCH * NOUT) return;
    int c = idx / NOUT, m = idx - c * NOUT;
    int b = m / OB2, o = m - b * OB2;
    float alpha = alpha_leak[0];
    float beta = powf(alpha, (float)DSR);
    float dec = powf(beta, (float)(o + 1));
    out[idx] += dec * D[c * NBLK + b];
}

extern "C" void kernel_launch(void* const* d_in, const int* in_sizes, int n_in,
                              void* d_out, int out_size, void* d_ws, size_t ws_size,
                              hipStream_t stream) {
    const float* x  = (const float*)d_in[0];
    const float* Hr = (const float*)d_in[1];
    const float* Hi = (const float*)d_in[2];
    const float* ac = (const float*)d_in[3];
    const float* al = (const float*)d_in[4];
    const float* li = (const float*)d_in[5];
    float* out = (float*)d_out;

    char* ws = (char*)d_ws;
    size_t off = 0;
    auto alloc = [&](size_t bytes) -> void* {
        void* p = ws + off;
        off += (bytes + 255) & ~(size_t)255;
        return p;
    };
    float2* Xf     = (float2*)alloc((size_t)LN * sizeof(float2));
    float*  comp   = (float*) alloc((size_t)NCH * LN * sizeof(float));
    float*  cOut   = (float*) alloc((size_t)NCH * NBLK * sizeof(float));
    float*  Dbuf   = (float*) alloc((size_t)NCH * NBLK * sizeof(float));
    size_t remain = (ws_size > off) ? (ws_size - off) : 0;
    int chunk = (int)(remain / ((size_t)LN * sizeof(float2)));
    if (chunk > NPAIR) chunk = NPAIR;
    if (chunk < 2)     chunk = 2;
    float2* bufA = (float2*)alloc((size_t)chunk * LN * sizeof(float2));

    dim3 tb(32, 8, 1);

    // ---- forward FFT of x (four-step with transposes; small, one signal) ----
    float2* fA = bufA;
    float2* fB = bufA + LN;
    pack_x<<<LN / 256, 256, 0, stream>>>(x, fA);
    transpose_c<<<dim3(N2/32, N1/32, 1), tb, 0, stream>>>(fA, fB, N1, N2);
    fft_rows<N1, -1, 1><<<N2, 256, 0, stream>>>(fB, fB, N2);
    transpose_c<<<dim3(N1/32, N2/32, 1), tb, 0, stream>>>(fB, fA, N2, N1);
    fft_rows<N2, -1, 0><<<N1, 256, 0, stream>>>(fA, fA, N1);
    transpose_c<<<dim3(N2/32, N1/32, 1), tb, 0, stream>>>(fA, Xf, N1, N2);

    // ---- batched inverse FFTs: build_w4 -> colFFT(in-place) -> rowFFT -> finish ----
    for (int ci = 0; ci < NPAIR; ci += chunk) {
        int np = NPAIR - ci; if (np > chunk) np = chunk;
        build_w4<<<dim3(LN/2/SB, np), 256, 0, stream>>>(Hr, Hi, Xf, bufA, ci);
        kB<<<dim3(64, np), 1024, 0, stream>>>(bufA);
        fft_rows<N2, 1, 0><<<N1 * np, 256, 0, stream>>>(bufA, bufA, N1);
        ifft_finish<<<dim3(32, 16, np), dim3(8, 32), 0, stream>>>(bufA, comp, ac, ci);
    }

    // ---- leaky integration (time-domain, exact to fp precision) + downsample ----
    iir_part1<<<dim3(NBLK, NCH, 1), 256, 0, stream>>>(comp, al, li, out, cOut);
    iir_part2<<<1, 256, 0, stream>>>(comp, al, li, cOut, Dbuf);
    iir_part3<<<(NCH * NOUT + 255) / 256, 256, 0, stream>>>(Dbuf, al, out);
}